// Round 4
// baseline (7641.028 us; speedup 1.0000x reference)
//
#include <hip/hip_runtime.h>
#include <hip/hip_bf16.h>

// ByteLevelDecoder: B=2,S=256,H=1024, BH=384,NH=8,HD=48, P=4,S_C=12,L=4,V=258,T=16
// Persistent kernel, 1 block = 2 sequences, 768 threads = 12 waves/CU.
// Round 12: __launch_bounds__(768, 3) — round 2/3's spill (WRITE 6GB, VGPR
// pinned at 84) was the allocator capping VGPRs at 512/6=85 for a 2-blocks/CU
// occupancy the 256-block grid can never use. Declaring 3 waves/EU raises the
// cap to ~170 so the named ping-pong dbuf sets actually live in registers.
// Everything else identical to round 11 (named dbuf QKV/Wo/W1/W2, fused NT=1
// softmax, split-s epilogues, global f16 KV, gamma-folded weights, split-K).

constexpr int H_IN  = 1024;
constexpr int BH    = 384;
constexpr int NH    = 8;
constexpr int HD    = 48;
constexpr int PP    = 4;
constexpr int S_CNT = 12;
constexpr int NL    = 4;
constexpr int NV    = 258;
constexpr int TT    = 16;
constexpr int NSEQ  = 512;
constexpr int EOS_I = 257;
constexpr int NTH   = 768;
constexpr float RSCALE = 0.14433756729740646f;  // 1/sqrt(48)

typedef _Float16 h2 __attribute__((ext_vector_type(2)));
typedef _Float16 h8 __attribute__((ext_vector_type(8)));

union W16 { h8 v8; h2 h[4]; _Float16 e[8]; };

template<int N> struct IC { static constexpr int value = N; };

__device__ __forceinline__ float fdot2(h2 a, h2 b, float c) {
#if __has_builtin(__builtin_amdgcn_fdot2)
  return __builtin_amdgcn_fdot2(a, b, c, false);
#else
  return c + (float)a.x * (float)b.x + (float)a.y * (float)b.y;
#endif
}

// ---- repack prepass: dst[j8*C + c] = {g[8j8+r]*src[8*j8+r][c]}_{r=0..7} ----
__global__ __launch_bounds__(256)
void pack8_kernel(const float* __restrict__ src, const float* __restrict__ g,
                  h8* __restrict__ dst, int C) {
  int c  = blockIdx.x * 256 + threadIdx.x;
  int j8 = blockIdx.y;
  if (c < C) {
    h8 v;
    #pragma unroll
    for (int r = 0; r < 8; r++) {
      int row = 8 * j8 + r;
      float s = g ? g[row] : 1.0f;
      v[r] = (_Float16)(src[(size_t)row * C + c] * s);
    }
    dst[(size_t)j8 * C + c] = v;
  }
}

// ==== straight-line named ping-pong macros (NO runtime-indexed reg arrays) ====
#define QKV_DECL(S) W16 S##q0, S##q1, S##q2, S##q3, S##k0, S##k1, S##k2, S##k3, \
                        S##v0, S##v1, S##v2, S##v3;
#define QKV_LOAD(S, b) \
  S##q0.v8 = Wq8[wb + (size_t)((b) + 0) * BH]; \
  S##q1.v8 = Wq8[wb + (size_t)((b) + 1) * BH]; \
  S##q2.v8 = Wq8[wb + (size_t)((b) + 2) * BH]; \
  S##q3.v8 = Wq8[wb + (size_t)((b) + 3) * BH]; \
  S##k0.v8 = Wk8[wb + (size_t)((b) + 0) * BH]; \
  S##k1.v8 = Wk8[wb + (size_t)((b) + 1) * BH]; \
  S##k2.v8 = Wk8[wb + (size_t)((b) + 2) * BH]; \
  S##k3.v8 = Wk8[wb + (size_t)((b) + 3) * BH]; \
  S##v0.v8 = Wv8[wb + (size_t)((b) + 0) * BH]; \
  S##v1.v8 = Wv8[wb + (size_t)((b) + 1) * BH]; \
  S##v2.v8 = Wv8[wb + (size_t)((b) + 2) * BH]; \
  S##v3.v8 = Wv8[wb + (size_t)((b) + 3) * BH];
#define QKV_COMP(S, b) \
  _Pragma("unroll") \
  for (int s_ = 0; s_ < 2; s_++) { \
    _Pragma("unroll") \
    for (int t_ = 0; t_ < NT; t_++) { \
      W16 h0_, h1_, h2_, h3_; \
      h0_.v8 = *(const h8*)&xh[s_][t_][(kg * 24 + (b) + 0) * 8]; \
      h1_.v8 = *(const h8*)&xh[s_][t_][(kg * 24 + (b) + 1) * 8]; \
      h2_.v8 = *(const h8*)&xh[s_][t_][(kg * 24 + (b) + 2) * 8]; \
      h3_.v8 = *(const h8*)&xh[s_][t_][(kg * 24 + (b) + 3) * 8]; \
      _Pragma("unroll") \
      for (int r_ = 0; r_ < 4; r_++) { \
        aq[s_][t_] = fdot2(h0_.h[r_], S##q0.h[r_], aq[s_][t_]); \
        ak[s_][t_] = fdot2(h0_.h[r_], S##k0.h[r_], ak[s_][t_]); \
        av[s_][t_] = fdot2(h0_.h[r_], S##v0.h[r_], av[s_][t_]); \
        aq[s_][t_] = fdot2(h1_.h[r_], S##q1.h[r_], aq[s_][t_]); \
        ak[s_][t_] = fdot2(h1_.h[r_], S##k1.h[r_], ak[s_][t_]); \
        av[s_][t_] = fdot2(h1_.h[r_], S##v1.h[r_], av[s_][t_]); \
        aq[s_][t_] = fdot2(h2_.h[r_], S##q2.h[r_], aq[s_][t_]); \
        ak[s_][t_] = fdot2(h2_.h[r_], S##k2.h[r_], ak[s_][t_]); \
        av[s_][t_] = fdot2(h2_.h[r_], S##v2.h[r_], av[s_][t_]); \
        aq[s_][t_] = fdot2(h3_.h[r_], S##q3.h[r_], aq[s_][t_]); \
        ak[s_][t_] = fdot2(h3_.h[r_], S##k3.h[r_], ak[s_][t_]); \
        av[s_][t_] = fdot2(h3_.h[r_], S##v3.h[r_], av[s_][t_]); \
      } } }

#define WO_DECL(S) W16 S##o0, S##o1, S##o2, S##o3, S##o4, S##o5, S##o6, S##o7;
#define WO_LOAD(S, b) \
  S##o0.v8 = Wo8[wb + (size_t)((b) + 0) * BH]; \
  S##o1.v8 = Wo8[wb + (size_t)((b) + 1) * BH]; \
  S##o2.v8 = Wo8[wb + (size_t)((b) + 2) * BH]; \
  S##o3.v8 = Wo8[wb + (size_t)((b) + 3) * BH]; \
  S##o4.v8 = Wo8[wb + (size_t)((b) + 4) * BH]; \
  S##o5.v8 = Wo8[wb + (size_t)((b) + 5) * BH]; \
  S##o6.v8 = Wo8[wb + (size_t)((b) + 6) * BH]; \
  S##o7.v8 = Wo8[wb + (size_t)((b) + 7) * BH];
#define WO_COMP(S, b) \
  _Pragma("unroll") \
  for (int s_ = 0; s_ < 2; s_++) { \
    _Pragma("unroll") \
    for (int t_ = 0; t_ < NT; t_++) { \
      W16 h0_, h1_, h2_, h3_, h4_, h5_, h6_, h7_; \
      h0_.v8 = *(const h8*)&oh[s_][t_][(kg * 24 + (b) + 0) * 8]; \
      h1_.v8 = *(const h8*)&oh[s_][t_][(kg * 24 + (b) + 1) * 8]; \
      h2_.v8 = *(const h8*)&oh[s_][t_][(kg * 24 + (b) + 2) * 8]; \
      h3_.v8 = *(const h8*)&oh[s_][t_][(kg * 24 + (b) + 3) * 8]; \
      h4_.v8 = *(const h8*)&oh[s_][t_][(kg * 24 + (b) + 4) * 8]; \
      h5_.v8 = *(const h8*)&oh[s_][t_][(kg * 24 + (b) + 5) * 8]; \
      h6_.v8 = *(const h8*)&oh[s_][t_][(kg * 24 + (b) + 6) * 8]; \
      h7_.v8 = *(const h8*)&oh[s_][t_][(kg * 24 + (b) + 7) * 8]; \
      _Pragma("unroll") \
      for (int r_ = 0; r_ < 4; r_++) { \
        ao[s_][t_] = fdot2(h0_.h[r_], S##o0.h[r_], ao[s_][t_]); \
        ao[s_][t_] = fdot2(h1_.h[r_], S##o1.h[r_], ao[s_][t_]); \
        ao[s_][t_] = fdot2(h2_.h[r_], S##o2.h[r_], ao[s_][t_]); \
        ao[s_][t_] = fdot2(h3_.h[r_], S##o3.h[r_], ao[s_][t_]); \
        ao[s_][t_] = fdot2(h4_.h[r_], S##o4.h[r_], ao[s_][t_]); \
        ao[s_][t_] = fdot2(h5_.h[r_], S##o5.h[r_], ao[s_][t_]); \
        ao[s_][t_] = fdot2(h6_.h[r_], S##o6.h[r_], ao[s_][t_]); \
        ao[s_][t_] = fdot2(h7_.h[r_], S##o7.h[r_], ao[s_][t_]); \
      } } }

#define W1_DECL(S) W16 S##a0, S##a1, S##a2, S##a3, S##b0, S##b1, S##b2, S##b3;
#define W1_LOAD(S, b) \
  S##a0.v8 = W18[((size_t)(l * 48 + (b) + 0)) * (4 * BH) + tid]; \
  S##a1.v8 = W18[((size_t)(l * 48 + (b) + 1)) * (4 * BH) + tid]; \
  S##a2.v8 = W18[((size_t)(l * 48 + (b) + 2)) * (4 * BH) + tid]; \
  S##a3.v8 = W18[((size_t)(l * 48 + (b) + 3)) * (4 * BH) + tid]; \
  S##b0.v8 = W18[((size_t)(l * 48 + (b) + 0)) * (4 * BH) + tid + NTH]; \
  S##b1.v8 = W18[((size_t)(l * 48 + (b) + 1)) * (4 * BH) + tid + NTH]; \
  S##b2.v8 = W18[((size_t)(l * 48 + (b) + 2)) * (4 * BH) + tid + NTH]; \
  S##b3.v8 = W18[((size_t)(l * 48 + (b) + 3)) * (4 * BH) + tid + NTH];
#define W1_COMP(S, b) \
  _Pragma("unroll") \
  for (int s_ = 0; s_ < 2; s_++) { \
    _Pragma("unroll") \
    for (int t_ = 0; t_ < NT; t_++) { \
      W16 h0_, h1_, h2_, h3_; \
      h0_.v8 = *(const h8*)&xh[s_][t_][((b) + 0) * 8]; \
      h1_.v8 = *(const h8*)&xh[s_][t_][((b) + 1) * 8]; \
      h2_.v8 = *(const h8*)&xh[s_][t_][((b) + 2) * 8]; \
      h3_.v8 = *(const h8*)&xh[s_][t_][((b) + 3) * 8]; \
      _Pragma("unroll") \
      for (int r_ = 0; r_ < 4; r_++) { \
        a1[s_][t_][0] = fdot2(h0_.h[r_], S##a0.h[r_], a1[s_][t_][0]); \
        a1[s_][t_][1] = fdot2(h0_.h[r_], S##b0.h[r_], a1[s_][t_][1]); \
        a1[s_][t_][0] = fdot2(h1_.h[r_], S##a1.h[r_], a1[s_][t_][0]); \
        a1[s_][t_][1] = fdot2(h1_.h[r_], S##b1.h[r_], a1[s_][t_][1]); \
        a1[s_][t_][0] = fdot2(h2_.h[r_], S##a2.h[r_], a1[s_][t_][0]); \
        a1[s_][t_][1] = fdot2(h2_.h[r_], S##b2.h[r_], a1[s_][t_][1]); \
        a1[s_][t_][0] = fdot2(h3_.h[r_], S##a3.h[r_], a1[s_][t_][0]); \
        a1[s_][t_][1] = fdot2(h3_.h[r_], S##b3.h[r_], a1[s_][t_][1]); \
      } } }

#define W2_DECL(S) W16 S##g0, S##g1, S##g2, S##g3, S##g4, S##g5, S##g6, S##g7;
#define W2_LOAD(S, b) \
  S##g0.v8 = W28[((size_t)(l * 192 + kg * 96 + (b) + 0)) * BH + col]; \
  S##g1.v8 = W28[((size_t)(l * 192 + kg * 96 + (b) + 1)) * BH + col]; \
  S##g2.v8 = W28[((size_t)(l * 192 + kg * 96 + (b) + 2)) * BH + col]; \
  S##g3.v8 = W28[((size_t)(l * 192 + kg * 96 + (b) + 3)) * BH + col]; \
  S##g4.v8 = W28[((size_t)(l * 192 + kg * 96 + (b) + 4)) * BH + col]; \
  S##g5.v8 = W28[((size_t)(l * 192 + kg * 96 + (b) + 5)) * BH + col]; \
  S##g6.v8 = W28[((size_t)(l * 192 + kg * 96 + (b) + 6)) * BH + col]; \
  S##g7.v8 = W28[((size_t)(l * 192 + kg * 96 + (b) + 7)) * BH + col];
#define W2_COMP(S, b) \
  _Pragma("unroll") \
  for (int s_ = 0; s_ < 2; s_++) { \
    _Pragma("unroll") \
    for (int t_ = 0; t_ < NT; t_++) { \
      W16 f0_, f1_, f2_, f3_, f4_, f5_, f6_, f7_; \
      f0_.v8 = *(const h8*)&scr.ffn.f1h[s_][t_][(kg * 96 + (b) + 0) * 8]; \
      f1_.v8 = *(const h8*)&scr.ffn.f1h[s_][t_][(kg * 96 + (b) + 1) * 8]; \
      f2_.v8 = *(const h8*)&scr.ffn.f1h[s_][t_][(kg * 96 + (b) + 2) * 8]; \
      f3_.v8 = *(const h8*)&scr.ffn.f1h[s_][t_][(kg * 96 + (b) + 3) * 8]; \
      f4_.v8 = *(const h8*)&scr.ffn.f1h[s_][t_][(kg * 96 + (b) + 4) * 8]; \
      f5_.v8 = *(const h8*)&scr.ffn.f1h[s_][t_][(kg * 96 + (b) + 5) * 8]; \
      f6_.v8 = *(const h8*)&scr.ffn.f1h[s_][t_][(kg * 96 + (b) + 6) * 8]; \
      f7_.v8 = *(const h8*)&scr.ffn.f1h[s_][t_][(kg * 96 + (b) + 7) * 8]; \
      _Pragma("unroll") \
      for (int r_ = 0; r_ < 4; r_++) { \
        a2[s_][t_] = fdot2(f0_.h[r_], S##g0.h[r_], a2[s_][t_]); \
        a2[s_][t_] = fdot2(f1_.h[r_], S##g1.h[r_], a2[s_][t_]); \
        a2[s_][t_] = fdot2(f2_.h[r_], S##g2.h[r_], a2[s_][t_]); \
        a2[s_][t_] = fdot2(f3_.h[r_], S##g3.h[r_], a2[s_][t_]); \
        a2[s_][t_] = fdot2(f4_.h[r_], S##g4.h[r_], a2[s_][t_]); \
        a2[s_][t_] = fdot2(f5_.h[r_], S##g5.h[r_], a2[s_][t_]); \
        a2[s_][t_] = fdot2(f6_.h[r_], S##g6.h[r_], a2[s_][t_]); \
        a2[s_][t_] = fdot2(f7_.h[r_], S##g7.h[r_], a2[s_][t_]); \
      } } }

__global__ __launch_bounds__(NTH, 3)
void decoder_kernel(const float* __restrict__ x,
                    const h8* __restrict__ Wproj8,   // [128][1536]
                    const h8* __restrict__ Wq8,      // [l*48][384], gamma-folded
                    const h8* __restrict__ Wk8,
                    const h8* __restrict__ Wv8,
                    const h8* __restrict__ Wo8,
                    const h8* __restrict__ W18,      // [l*48][1536], gamma-folded
                    const h8* __restrict__ W28,      // [l*192][384]
                    const h8* __restrict__ Wlm8,     // [48][258]
                    float* __restrict__ out,
                    _Float16* __restrict__ kbuf,
                    _Float16* __restrict__ vbuf)
{
  __shared__ float xs[2][4][BH];                     // residual stream (f32)
  __shared__ __align__(16) _Float16 xh[2][4][BH];    // residual as f16 (GEMM input)
  __shared__ __align__(16) _Float16 qh[2][4][BH];    // q (f16, pre-scaled)
  __shared__ __align__(16) _Float16 oh[2][4][BH];    // attention out (f16)
  __shared__ float sc[2][NH][4][TT];
  __shared__ __align__(16) union Scr {
    float qkvp[3][2][4][BH];                         // QKV split-K partials (36KB)
    float wop[2][4][BH];                             // Wo partials (12KB)
    struct { __align__(16) _Float16 f1h[2][4][4*BH]; // gelu out f16 (24KB)
             float w2p[2][4][BH]; } ffn;             // W2 partials (12KB)
    __align__(16) _Float16 xin[2][H_IN];             // staged input x (4KB)
  } scr;
  __shared__ float redsq[2][4][6];                   // x^2 wave-sums per (s,tok)
  __shared__ float redv[12];
  __shared__ int   redi[12];
  __shared__ int   fin[2];

  const int tid = threadIdx.x;
  const int kg  = tid / BH;        // split-K group (0/1); also seq index
  const int col = tid - kg * BH;   // 0..383
  const int sq  = kg;
  const int wid = tid >> 6;        // wave id 0..11
  const int w6  = wid % 6;
  const int seq0 = blockIdx.x * 2;

  if (tid < 2) fin[tid] = 0;

  // ---- stage x as f16 ----
  for (int s = 0; s < 2; s++) {
    const size_t base = (size_t)(seq0 + s) * H_IN;
    for (int j = tid; j < H_IN; j += NTH) scr.xin[s][j] = (_Float16)x[base + j];
  }
  __syncthreads();
  // ---- x0 = (x_row @ Wproj).reshape(P, BH); epilogue fuses f16 stage + x^2 ----
  {
    float acc[2][2] = {};
    for (int j8 = 0; j8 < H_IN / 8; j8 += 4) {
      W16 w0[4], w1[4];
      #pragma unroll
      for (int u = 0; u < 4; u++) {
        w0[u].v8 = Wproj8[(size_t)(j8 + u) * (PP * BH) + tid];
        w1[u].v8 = Wproj8[(size_t)(j8 + u) * (PP * BH) + tid + NTH];
      }
      #pragma unroll
      for (int u = 0; u < 4; u++)
        #pragma unroll
        for (int s = 0; s < 2; s++) {
          W16 hv; hv.v8 = *(const h8*)&scr.xin[s][(j8 + u) * 8];
          #pragma unroll
          for (int r = 0; r < 4; r++) {
            acc[s][0] = fdot2(hv.h[r], w0[u].h[r], acc[s][0]);
            acc[s][1] = fdot2(hv.h[r], w1[u].h[r], acc[s][1]);
          }
        }
    }
    const int m0 = tid / BH, cc = tid - m0 * BH;     // tok pair (m0, m0+2)
    #pragma unroll
    for (int s = 0; s < 2; s++) {
      xs[s][m0][cc]     = acc[s][0];  xh[s][m0][cc]     = (_Float16)acc[s][0];
      xs[s][m0 + 2][cc] = acc[s][1];  xh[s][m0 + 2][cc] = (_Float16)acc[s][1];
      float r0 = acc[s][0] * acc[s][0], r1 = acc[s][1] * acc[s][1];
      #pragma unroll
      for (int off = 32; off; off >>= 1) {
        r0 += __shfl_down(r0, off, 64); r1 += __shfl_down(r1, off, 64);
      }
      if ((tid & 63) == 0) { redsq[s][m0][w6] = r0; redsq[s][m0 + 2][w6] = r1; }
    }
  }
  __syncthreads();

  auto layers = [&](auto ntc, int pos, bool causal) {
    constexpr int NT = decltype(ntc)::value;
    const int nk = pos + NT;
    for (int l = 0; l < NL; l++) {
      // ==== q,k,v = sca * (x @ gW) (split-K, named dbuf; split-s epilogue) ====
      {
        const size_t wb = ((size_t)l * 48 + kg * 24) * BH + col;
        float aq[2][NT] = {}, ak[2][NT] = {}, av[2][NT] = {};
        QKV_DECL(A) QKV_DECL(B)
        QKV_LOAD(A, 0)
        QKV_LOAD(B, 4)
        QKV_COMP(A, 0)
        QKV_LOAD(A, 8)
        QKV_COMP(B, 4)
        QKV_LOAD(B, 12)
        QKV_COMP(A, 8)
        QKV_LOAD(A, 16)
        QKV_COMP(B, 12)
        QKV_LOAD(B, 20)
        QKV_COMP(A, 16)
        QKV_COMP(B, 20)
        {
          const int so = kg ^ 1;  // publish partials for the OTHER seq
          #pragma unroll
          for (int tok = 0; tok < NT; tok++) {
            scr.qkvp[0][so][tok][col] = aq[so][tok];
            scr.qkvp[1][so][tok][col] = ak[so][tok];
            scr.qkvp[2][so][tok][col] = av[so][tok];
          }
        }
        __syncthreads();
        {
          const int s = kg;       // finalize own seq
          const size_t cb = (((size_t)(seq0 + s) * NL + l) * TT + pos) * BH + col;
          #pragma unroll
          for (int tok = 0; tok < NT; tok++) {
            float ss = redsq[s][tok][0] + redsq[s][tok][1] + redsq[s][tok][2] +
                       redsq[s][tok][3] + redsq[s][tok][4] + redsq[s][tok][5];
            float sca = rsqrtf(ss * (1.0f / BH) + 1e-5f);
            qh[s][tok][col] = (_Float16)((aq[s][tok] + scr.qkvp[0][s][tok][col]) * sca * RSCALE);
            kbuf[cb + (size_t)tok * BH] = (_Float16)((ak[s][tok] + scr.qkvp[1][s][tok][col]) * sca);
            vbuf[cb + (size_t)tok * BH] = (_Float16)((av[s][tok] + scr.qkvp[2][s][tok][col]) * sca);
          }
        }
        __syncthreads();
      }
      // ==== scores + softmax (RSCALE pre-folded into q) ====
      if constexpr (NT == 1) {
        // fused: 256 threads, one (s,h,j) per lane; shfl reduce in 16-lane groups
        if (tid < 2 * NH * TT) {
          const int s = tid >> 7, r = tid & 127, h = r >> 4, j = r & 15;
          float d = -1e30f;
          if (j < nk) {
            const h8* kp8 = (const h8*)(kbuf + (((size_t)(seq0 + s) * NL + l) * TT + j) * BH + h * HD);
            d = 0.f;
            #pragma unroll
            for (int c6 = 0; c6 < 6; c6++) {
              W16 kk, qq;
              kk.v8 = kp8[c6];
              qq.v8 = *(const h8*)&qh[s][0][h * HD + c6 * 8];
              #pragma unroll
              for (int rr = 0; rr < 4; rr++) d = fdot2(qq.h[rr], kk.h[rr], d);
            }
          }
          float m = d;
          #pragma unroll
          for (int off = 8; off; off >>= 1) m = fmaxf(m, __shfl_xor(m, off, 16));
          float e = expf(d - m);
          float den = e;
          #pragma unroll
          for (int off = 8; off; off >>= 1) den += __shfl_xor(den, off, 16);
          sc[s][h][0][j] = e * (1.0f / den);
        }
        __syncthreads();
      } else {
        {
          const int nu = 2 * NH * NT * nk;   // step0: 256
          if (tid < nu) {
            int s = tid / (NH * NT * nk), r = tid % (NH * NT * nk);
            int h = r / (NT * nk); int r2 = r % (NT * nk);
            int qi = r2 / nk, j = r2 % nk;
            float d;
            if (causal && j > pos + qi) d = -1e30f;
            else {
              const h8* kp8 = (const h8*)(kbuf + (((size_t)(seq0 + s) * NL + l) * TT + j) * BH + h * HD);
              d = 0.f;
              #pragma unroll
              for (int c6 = 0; c6 < 6; c6++) {
                W16 kk, qq;
                kk.v8 = kp8[c6];
                qq.v8 = *(const h8*)&qh[s][qi][h * HD + c6 * 8];
                #pragma unroll
                for (int rr = 0; rr < 4; rr++) d = fdot2(qq.h[rr], kk.h[rr], d);
              }
            }
            sc[s][h][qi][j] = d;
          }
        }
        __syncthreads();
        {
          const int nr = 2 * NH * NT;
          if (tid < nr) {
            int s = tid / (NH * NT), r = tid % (NH * NT);
            int h = r / NT, qi = r % NT;
            float m = -3.0e38f;
            for (int j = 0; j < nk; j++) m = fmaxf(m, sc[s][h][qi][j]);
            float den = 0.f;
            for (int j = 0; j < nk; j++) {
              float e = expf(sc[s][h][qi][j] - m);
              sc[s][h][qi][j] = e; den += e;
            }
            float inv = 1.0f / den;
            for (int j = 0; j < nk; j++) sc[s][h][qi][j] *= inv;
          }
        }
        __syncthreads();
      }
      // ==== o = p @ V ====
      {
        const size_t vb = (((size_t)(seq0 + sq) * NL + l) * TT) * BH + col;
        const int h = col / HD;
        #pragma unroll
        for (int tok = 0; tok < NT; tok++) {
          float acc = 0.f;
          int j = 0;
          for (; j + 4 <= nk; j += 4) {
            float v0 = (float)vbuf[vb + (size_t)(j + 0) * BH];
            float v1 = (float)vbuf[vb + (size_t)(j + 1) * BH];
            float v2 = (float)vbuf[vb + (size_t)(j + 2) * BH];
            float v3 = (float)vbuf[vb + (size_t)(j + 3) * BH];
            acc += sc[sq][h][tok][j] * v0 + sc[sq][h][tok][j + 1] * v1 +
                   sc[sq][h][tok][j + 2] * v2 + sc[sq][h][tok][j + 3] * v3;
          }
          for (; j < nk; j++)
            acc += sc[sq][h][tok][j] * (float)vbuf[vb + (size_t)j * BH];
          oh[sq][tok][col] = (_Float16)acc;
        }
      }
      __syncthreads();
      // ==== x += o @ Wo (split-K, named dbuf; split-s epilogue) ====
      {
        const size_t wb = ((size_t)l * 48 + kg * 24) * BH + col;
        float ao[2][NT] = {};
        WO_DECL(A) WO_DECL(B)
        WO_LOAD(A, 0)
        WO_LOAD(B, 8)
        WO_COMP(A, 0)
        WO_LOAD(A, 16)
        WO_COMP(B, 8)
        WO_COMP(A, 16)
        {
          const int so = kg ^ 1;
          #pragma unroll
          for (int tok = 0; tok < NT; tok++) scr.wop[so][tok][col] = ao[so][tok];
        }
        __syncthreads();
        {
          const int s = kg;
          #pragma unroll
          for (int tok = 0; tok < NT; tok++) {
            float xn = xs[s][tok][col] + ao[s][tok] + scr.wop[s][tok][col];
            xs[s][tok][col] = xn; xh[s][tok][col] = (_Float16)xn;
            float r = xn * xn;
            #pragma unroll
            for (int off = 32; off; off >>= 1) r += __shfl_down(r, off, 64);
            if ((tid & 63) == 0) redsq[s][tok][w6] = r;
          }
        }
        __syncthreads();
      }
      // ==== x += gelu(sca2 * (x @ gW1)) @ W2 (named dbuf both GEMVs) ====
      {
        float a1[2][NT][2] = {};
        {
          W1_DECL(A) W1_DECL(B)
          W1_LOAD(A, 0)
          W1_LOAD(B, 4)
          W1_COMP(A, 0)
          W1_LOAD(A, 8)
          W1_COMP(B, 4)
          W1_LOAD(B, 12)
          W1_COMP(A, 8)
          W1_LOAD(A, 16)
          W1_COMP(B, 12)
          W1_LOAD(B, 20)
          W1_COMP(A, 16)
          W1_LOAD(A, 24)
          W1_COMP(B, 20)
          W1_LOAD(B, 28)
          W1_COMP(A, 24)
          W1_LOAD(A, 32)
          W1_COMP(B, 28)
          W1_LOAD(B, 36)
          W1_COMP(A, 32)
          W1_LOAD(A, 40)
          W1_COMP(B, 36)
          W1_LOAD(B, 44)
          W1_COMP(A, 40)
          W1_COMP(B, 44)
        }
        #pragma unroll
        for (int s = 0; s < 2; s++)
          #pragma unroll
          for (int t = 0; t < NT; t++) {
            float ss = redsq[s][t][0] + redsq[s][t][1] + redsq[s][t][2] +
                       redsq[s][t][3] + redsq[s][t][4] + redsq[s][t][5];
            float sca = rsqrtf(ss * (1.0f / BH) + 1e-5f);
            float z0 = a1[s][t][0] * sca, z1 = a1[s][t][1] * sca;
            scr.ffn.f1h[s][t][tid]       = (_Float16)(0.5f * z0 * (1.0f + erff(z0 * 0.7071067811865476f)));
            scr.ffn.f1h[s][t][tid + NTH] = (_Float16)(0.5f * z1 * (1.0f + erff(z1 * 0.7071067811865476f)));
          }
        __syncthreads();
        // W2: split-K, named dbuf; split-s epilogue fuses xh stage + x^2 sums
        {
          float a2[2][NT] = {};
          W2_DECL(A) W2_DECL(B)
          W2_LOAD(A, 0)
          W2_LOAD(B, 8)
          W2_COMP(A, 0)
          W2_LOAD(A, 16)
          W2_COMP(B, 8)
          W2_LOAD(B, 24)
          W2_COMP(A, 16)
          W2_LOAD(A, 32)
          W2_COMP(B, 24)
          W2_LOAD(B, 40)
          W2_COMP(A, 32)
          W2_LOAD(A, 48)
          W2_COMP(B, 40)
          W2_LOAD(B, 56)
          W2_COMP(A, 48)
          W2_LOAD(A, 64)
          W2_COMP(B, 56)
          W2_LOAD(B, 72)
          W2_COMP(A, 64)
          W2_LOAD(A, 80)
          W2_COMP(B, 72)
          W2_LOAD(B, 88)
          W2_COMP(A, 80)
          W2_COMP(B, 88)
          {
            const int so = kg ^ 1;
            #pragma unroll
            for (int t = 0; t < NT; t++) scr.ffn.w2p[so][t][col] = a2[so][t];
          }
          __syncthreads();
          {
            const int s = kg;
            #pragma unroll
            for (int t = 0; t < NT; t++) {
              float xn = xs[s][t][col] + a2[s][t] + scr.ffn.w2p[s][t][col];
              xs[s][t][col] = xn; xh[s][t][col] = (_Float16)xn;
              float r = xn * xn;
              #pragma unroll
              for (int off = 32; off; off >>= 1) r += __shfl_down(r, off, 64);
              if ((tid & 63) == 0) redsq[s][t][w6] = r;
            }
          }
          __syncthreads();
        }
      }
    }
  };

  for (int i = 0; i < S_CNT; i++) {
    int grow;
    if (i == 0) { layers(IC<4>{}, 0, true);           grow = 3; }
    else        { layers(IC<1>{}, PP + i - 1, false); grow = 0; }

    // ---- phase A: argmax partials + next-token copy (fused f16 stage + sums) ----
    {
      float gen = xs[sq][grow][col];
      float v = gen; int idx = col;
      #pragma unroll
      for (int off = 32; off; off >>= 1) {
        float v2 = __shfl_down(v, off, 64); int i2 = __shfl_down(idx, off, 64);
        if (v2 > v || (v2 == v && i2 < idx)) { v = v2; idx = i2; }
      }
      if ((tid & 63) == 0) { redv[wid] = v; redi[wid] = idx; }
      float nxt = fin[sq] ? 0.0f : gen;
      xs[sq][0][col] = nxt; xh[sq][0][col] = (_Float16)nxt;
      float r = nxt * nxt;
      #pragma unroll
      for (int off = 32; off; off >>= 1) r += __shfl_down(r, off, 64);
      if ((tid & 63) == 0) redsq[sq][0][w6] = r;
      __syncthreads();
    }
    // ---- phase B: argmax finalize (+fin update by same thread) + fin-free logits ----
    {
      if (col == 0) {
        const int b = sq * 6;
        float bv = redv[b]; int bi = redi[b];
        for (int w = 1; w < 6; w++)
          if (redv[b + w] > bv || (redv[b + w] == bv && redi[b + w] < bi)) {
            bv = redv[b + w]; bi = redi[b + w];
          }
        if (bi == EOS_I) fin[sq] = 1;
      }
      if (col < NV) {
        float acc = 0.f;
        for (int j8 = 0; j8 < 48; j8 += 8) {
          W16 w[8];
          #pragma unroll
          for (int u = 0; u < 8; u++) w[u].v8 = Wlm8[(size_t)(j8 + u) * NV + col];
          #pragma unroll
          for (int u = 0; u < 8; u++) {
            W16 gv; gv.v8 = *(const h8*)&xh[sq][0][(j8 + u) * 8];
            #pragma unroll
            for (int r = 0; r < 4; r++) acc = fdot2(gv.h[r], w[u].h[r], acc);
          }
        }
        out[((size_t)(seq0 + sq) * S_CNT + i) * NV + col] = acc;
      }
      __syncthreads();
    }
  }
}

extern "C" void kernel_launch(void* const* d_in, const int* in_sizes, int n_in,
                              void* d_out, int out_size, void* d_ws, size_t ws_size,
                              hipStream_t stream) {
  const float* x     = (const float*)d_in[0];
  // d_in[1] = target (unused)
  const float* Wproj = (const float*)d_in[2];
  const float* an    = (const float*)d_in[3];
  const float* Wq    = (const float*)d_in[4];
  const float* Wk    = (const float*)d_in[5];
  const float* Wv    = (const float*)d_in[6];
  const float* Wo    = (const float*)d_in[7];
  const float* fn    = (const float*)d_in[8];
  const float* W1    = (const float*)d_in[9];
  const float* W2    = (const float*)d_in[10];
  const float* Wlm   = (const float*)d_in[11];
  float* out = (float*)d_out;
  (void)ws_size; (void)in_sizes; (void)n_in; (void)out_size;

  // ---- carve d_ws: h8-packed weights (gamma folded into Wq/Wk/Wv/W1), then f16 KV ----
  h8* w = (h8*)d_ws;
  const int n_proj = (H_IN / 8) * (PP * BH);
  const int n_qkvo = NL * (BH / 8) * BH;
  const int n_w1   = NL * (BH / 8) * (4 * BH);
  const int n_w2   = NL * (4 * BH / 8) * BH;
  const int n_lm   = (BH / 8) * NV;
  h8* Wproj_p = w;  w += n_proj;
  h8* Wq_p    = w;  w += n_qkvo;
  h8* Wk_p    = w;  w += n_qkvo;
  h8* Wv_p    = w;  w += n_qkvo;
  h8* Wo_p    = w;  w += n_qkvo;
  h8* W1_p    = w;  w += n_w1;
  h8* W2_p    = w;  w += n_w2;
  h8* Wlm_p   = w;  w += n_lm;
  const size_t kv_elems = (size_t)NSEQ * NL * TT * BH;
  _Float16* kbuf = (_Float16*)w;
  _Float16* vbuf = kbuf + kv_elems;

  auto pack = [&](const float* src, const float* g, h8* dst, int R, int C) {
    dim3 grid((C + 255) / 256, R / 8);
    pack8_kernel<<<grid, 256, 0, stream>>>(src, g, dst, C);
  };
  pack(Wproj, nullptr, Wproj_p, H_IN,        PP * BH);
  pack(Wq,    an,      Wq_p,    NL * BH,     BH);
  pack(Wk,    an,      Wk_p,    NL * BH,     BH);
  pack(Wv,    an,      Wv_p,    NL * BH,     BH);
  pack(Wo,    nullptr, Wo_p,    NL * BH,     BH);
  pack(W1,    fn,      W1_p,    NL * BH,     4 * BH);
  pack(W2,    nullptr, W2_p,    NL * 4 * BH, BH);
  pack(Wlm,   nullptr, Wlm_p,   BH,          NV);

  decoder_kernel<<<NSEQ / 2, NTH, 0, stream>>>(
      x, Wproj_p, Wq_p, Wk_p, Wv_p, Wo_p, W1_p, W2_p, Wlm_p, out, kbuf, vbuf);
}

// Round 5
// 2333.503 us; speedup vs baseline: 3.2745x; 3.2745x over previous
//
#include <hip/hip_runtime.h>
#include <hip/hip_bf16.h>

// ByteLevelDecoder: B=2,S=256,H=1024, BH=384,NH=8,HD=48, P=4,S_C=12,L=4,V=258,T=16
// Persistent kernel, 1 block = 2 sequences, 768 threads = 12 waves/CU.
// Round 13: back to the round-8 (2422us) structure — register-level dbuf is
// abandoned (VGPR cap pinned at 84 on this toolchain; launch_bounds(,3) is
// ignored; forced wide live ranges spill 6GB to scratch). Kept the three
// verified zero-pressure wins: (a) fused NT=1 scores+softmax (16-lane shfl,
// one barrier); (b) split-s epilogues (QKV/Wo/W2); (c) NEW: current-step K/V
// rows cached in LDS (k_cur/v_cur) so scores/pV skip the global round-trip on
// the freshest row; step0 never reads global KV.

constexpr int H_IN  = 1024;
constexpr int BH    = 384;
constexpr int NH    = 8;
constexpr int HD    = 48;
constexpr int PP    = 4;
constexpr int S_CNT = 12;
constexpr int NL    = 4;
constexpr int NV    = 258;
constexpr int TT    = 16;
constexpr int NSEQ  = 512;
constexpr int EOS_I = 257;
constexpr int NTH   = 768;
constexpr float RSCALE = 0.14433756729740646f;  // 1/sqrt(48)

typedef _Float16 h2 __attribute__((ext_vector_type(2)));
typedef _Float16 h8 __attribute__((ext_vector_type(8)));

union W16 { h8 v8; h2 h[4]; _Float16 e[8]; };

template<int N> struct IC { static constexpr int value = N; };

__device__ __forceinline__ float fdot2(h2 a, h2 b, float c) {
#if __has_builtin(__builtin_amdgcn_fdot2)
  return __builtin_amdgcn_fdot2(a, b, c, false);
#else
  return c + (float)a.x * (float)b.x + (float)a.y * (float)b.y;
#endif
}

// ---- repack prepass: dst[j8*C + c] = {g[8j8+r]*src[8*j8+r][c]}_{r=0..7} ----
__global__ __launch_bounds__(256)
void pack8_kernel(const float* __restrict__ src, const float* __restrict__ g,
                  h8* __restrict__ dst, int C) {
  int c  = blockIdx.x * 256 + threadIdx.x;
  int j8 = blockIdx.y;
  if (c < C) {
    h8 v;
    #pragma unroll
    for (int r = 0; r < 8; r++) {
      int row = 8 * j8 + r;
      float s = g ? g[row] : 1.0f;
      v[r] = (_Float16)(src[(size_t)row * C + c] * s);
    }
    dst[(size_t)j8 * C + c] = v;
  }
}

__global__ __launch_bounds__(NTH)
void decoder_kernel(const float* __restrict__ x,
                    const h8* __restrict__ Wproj8,   // [128][1536]
                    const h8* __restrict__ Wq8,      // [l*48][384], gamma-folded
                    const h8* __restrict__ Wk8,
                    const h8* __restrict__ Wv8,
                    const h8* __restrict__ Wo8,
                    const h8* __restrict__ W18,      // [l*48][1536], gamma-folded
                    const h8* __restrict__ W28,      // [l*192][384]
                    const h8* __restrict__ Wlm8,     // [48][258]
                    float* __restrict__ out,
                    _Float16* __restrict__ kbuf,
                    _Float16* __restrict__ vbuf)
{
  __shared__ float xs[2][4][BH];                     // residual stream (f32)
  __shared__ __align__(16) _Float16 xh[2][4][BH];    // residual as f16 (GEMM input)
  __shared__ __align__(16) _Float16 qh[2][4][BH];    // q (f16, pre-scaled)
  __shared__ __align__(16) _Float16 oh[2][4][BH];    // attention out (f16)
  __shared__ __align__(16) _Float16 k_cur[2][4][BH]; // this step's K rows (6KB)
  __shared__ __align__(16) _Float16 v_cur[2][4][BH]; // this step's V rows (6KB)
  __shared__ float sc[2][NH][4][TT];
  __shared__ __align__(16) union Scr {
    float qkvp[3][2][4][BH];                         // QKV split-K partials (36KB)
    float wop[2][4][BH];                             // Wo partials (12KB)
    struct { __align__(16) _Float16 f1h[2][4][4*BH]; // gelu out f16 (24KB)
             float w2p[2][4][BH]; } ffn;             // W2 partials (12KB)
    __align__(16) _Float16 xin[2][H_IN];             // staged input x (4KB)
  } scr;
  __shared__ float redsq[2][4][6];                   // x^2 wave-sums per (s,tok)
  __shared__ float redv[12];
  __shared__ int   redi[12];
  __shared__ int   fin[2];

  const int tid = threadIdx.x;
  const int kg  = tid / BH;        // split-K group (0/1); also seq index
  const int col = tid - kg * BH;   // 0..383
  const int sq  = kg;
  const int wid = tid >> 6;        // wave id 0..11
  const int w6  = wid % 6;
  const int seq0 = blockIdx.x * 2;

  if (tid < 2) fin[tid] = 0;

  // ---- stage x as f16 ----
  for (int s = 0; s < 2; s++) {
    const size_t base = (size_t)(seq0 + s) * H_IN;
    for (int j = tid; j < H_IN; j += NTH) scr.xin[s][j] = (_Float16)x[base + j];
  }
  __syncthreads();
  // ---- x0 = (x_row @ Wproj).reshape(P, BH); epilogue fuses f16 stage + x^2 sums ----
  {
    float acc[2][2] = {};
    for (int j8 = 0; j8 < H_IN / 8; j8 += 4) {
      W16 w0[4], w1[4];
      #pragma unroll
      for (int u = 0; u < 4; u++) {
        w0[u].v8 = Wproj8[(size_t)(j8 + u) * (PP * BH) + tid];
        w1[u].v8 = Wproj8[(size_t)(j8 + u) * (PP * BH) + tid + NTH];
      }
      #pragma unroll
      for (int u = 0; u < 4; u++)
        #pragma unroll
        for (int s = 0; s < 2; s++) {
          W16 hv; hv.v8 = *(const h8*)&scr.xin[s][(j8 + u) * 8];
          #pragma unroll
          for (int r = 0; r < 4; r++) {
            acc[s][0] = fdot2(hv.h[r], w0[u].h[r], acc[s][0]);
            acc[s][1] = fdot2(hv.h[r], w1[u].h[r], acc[s][1]);
          }
        }
    }
    const int m0 = tid / BH, cc = tid - m0 * BH;     // tok pair (m0, m0+2)
    #pragma unroll
    for (int s = 0; s < 2; s++) {
      xs[s][m0][cc]     = acc[s][0];  xh[s][m0][cc]     = (_Float16)acc[s][0];
      xs[s][m0 + 2][cc] = acc[s][1];  xh[s][m0 + 2][cc] = (_Float16)acc[s][1];
      float r0 = acc[s][0] * acc[s][0], r1 = acc[s][1] * acc[s][1];
      #pragma unroll
      for (int off = 32; off; off >>= 1) {
        r0 += __shfl_down(r0, off, 64); r1 += __shfl_down(r1, off, 64);
      }
      if ((tid & 63) == 0) { redsq[s][m0][w6] = r0; redsq[s][m0 + 2][w6] = r1; }
    }
  }
  __syncthreads();

  auto layers = [&](auto ntc, int pos, bool causal) {
    constexpr int NT = decltype(ntc)::value;
    const int nk = pos + NT;
    for (int l = 0; l < NL; l++) {
      // ==== q,k,v = sca * (x @ gW) (split-K; split-s epilogue) ====
      {
        const size_t wb = ((size_t)l * 48 + kg * 24) * BH + col;
        float aq[2][NT] = {}, ak[2][NT] = {}, av[2][NT] = {};
        for (int j8 = 0; j8 < 24; j8 += 4) {
          W16 wq[4], wk[4], wv[4];
          #pragma unroll
          for (int u = 0; u < 4; u++) {
            wq[u].v8 = Wq8[wb + (size_t)(j8 + u) * BH];
            wk[u].v8 = Wk8[wb + (size_t)(j8 + u) * BH];
            wv[u].v8 = Wv8[wb + (size_t)(j8 + u) * BH];
          }
          #pragma unroll
          for (int u = 0; u < 4; u++)
            #pragma unroll
            for (int s = 0; s < 2; s++)
              #pragma unroll
              for (int tok = 0; tok < NT; tok++) {
                W16 hv; hv.v8 = *(const h8*)&xh[s][tok][(kg * 24 + j8 + u) * 8];
                #pragma unroll
                for (int r = 0; r < 4; r++) {
                  aq[s][tok] = fdot2(hv.h[r], wq[u].h[r], aq[s][tok]);
                  ak[s][tok] = fdot2(hv.h[r], wk[u].h[r], ak[s][tok]);
                  av[s][tok] = fdot2(hv.h[r], wv[u].h[r], av[s][tok]);
                }
              }
        }
        {
          const int so = kg ^ 1;  // publish partials for the OTHER seq
          #pragma unroll
          for (int tok = 0; tok < NT; tok++) {
            scr.qkvp[0][so][tok][col] = aq[so][tok];
            scr.qkvp[1][so][tok][col] = ak[so][tok];
            scr.qkvp[2][so][tok][col] = av[so][tok];
          }
        }
        __syncthreads();
        {
          const int s = kg;       // finalize own seq
          const size_t cb = (((size_t)(seq0 + s) * NL + l) * TT + pos) * BH + col;
          #pragma unroll
          for (int tok = 0; tok < NT; tok++) {
            float ss = redsq[s][tok][0] + redsq[s][tok][1] + redsq[s][tok][2] +
                       redsq[s][tok][3] + redsq[s][tok][4] + redsq[s][tok][5];
            float sca = rsqrtf(ss * (1.0f / BH) + 1e-5f);
            float kv_ = (ak[s][tok] + scr.qkvp[1][s][tok][col]) * sca;
            float vv_ = (av[s][tok] + scr.qkvp[2][s][tok][col]) * sca;
            qh[s][tok][col] = (_Float16)((aq[s][tok] + scr.qkvp[0][s][tok][col]) * sca * RSCALE);
            k_cur[s][tok][col] = (_Float16)kv_;
            v_cur[s][tok][col] = (_Float16)vv_;
            kbuf[cb + (size_t)tok * BH] = (_Float16)kv_;
            vbuf[cb + (size_t)tok * BH] = (_Float16)vv_;
          }
        }
        __syncthreads();
      }
      // ==== scores + softmax (RSCALE pre-folded into q) ====
      if constexpr (NT == 1) {
        // fused: 256 threads, one (s,h,j) per lane; shfl reduce in 16-lane groups
        if (tid < 2 * NH * TT) {
          const int s = tid >> 7, r = tid & 127, h = r >> 4, j = r & 15;
          float d = -1e30f;
          if (j < nk) {
            const h8* kp8 = (j == pos)
                ? (const h8*)&k_cur[s][0][h * HD]
                : (const h8*)(kbuf + (((size_t)(seq0 + s) * NL + l) * TT + j) * BH + h * HD);
            d = 0.f;
            #pragma unroll
            for (int c6 = 0; c6 < 6; c6++) {
              W16 kk, qq;
              kk.v8 = kp8[c6];
              qq.v8 = *(const h8*)&qh[s][0][h * HD + c6 * 8];
              #pragma unroll
              for (int rr = 0; rr < 4; rr++) d = fdot2(qq.h[rr], kk.h[rr], d);
            }
          }
          float m = d;
          #pragma unroll
          for (int off = 8; off; off >>= 1) m = fmaxf(m, __shfl_xor(m, off, 16));
          float e = expf(d - m);
          float den = e;
          #pragma unroll
          for (int off = 8; off; off >>= 1) den += __shfl_xor(den, off, 16);
          sc[s][h][0][j] = e * (1.0f / den);
        }
        __syncthreads();
      } else {
        // step 0: all nk rows are current-step -> K from LDS only
        {
          const int nu = 2 * NH * NT * nk;   // 256
          if (tid < nu) {
            int s = tid / (NH * NT * nk), r = tid % (NH * NT * nk);
            int h = r / (NT * nk); int r2 = r % (NT * nk);
            int qi = r2 / nk, j = r2 % nk;
            float d;
            if (causal && j > pos + qi) d = -1e30f;
            else {
              d = 0.f;
              #pragma unroll
              for (int c6 = 0; c6 < 6; c6++) {
                W16 kk, qq;
                kk.v8 = *(const h8*)&k_cur[s][j][h * HD + c6 * 8];
                qq.v8 = *(const h8*)&qh[s][qi][h * HD + c6 * 8];
                #pragma unroll
                for (int rr = 0; rr < 4; rr++) d = fdot2(qq.h[rr], kk.h[rr], d);
              }
            }
            sc[s][h][qi][j] = d;
          }
        }
        __syncthreads();
        {
          const int nr = 2 * NH * NT;
          if (tid < nr) {
            int s = tid / (NH * NT), r = tid % (NH * NT);
            int h = r / NT, qi = r % NT;
            float m = -3.0e38f;
            for (int j = 0; j < nk; j++) m = fmaxf(m, sc[s][h][qi][j]);
            float den = 0.f;
            for (int j = 0; j < nk; j++) {
              float e = expf(sc[s][h][qi][j] - m);
              sc[s][h][qi][j] = e; den += e;
            }
            float inv = 1.0f / den;
            for (int j = 0; j < nk; j++) sc[s][h][qi][j] *= inv;
          }
        }
        __syncthreads();
      }
      // ==== o = p @ V (old rows from global, current rows from LDS) ====
      {
        const size_t vb = (((size_t)(seq0 + sq) * NL + l) * TT) * BH + col;
        const int h = col / HD;
        #pragma unroll
        for (int tok = 0; tok < NT; tok++) {
          float acc = 0.f;
          if constexpr (NT == 1) {
            int j = 0;
            for (; j + 4 <= pos; j += 4) {
              float v0 = (float)vbuf[vb + (size_t)(j + 0) * BH];
              float v1 = (float)vbuf[vb + (size_t)(j + 1) * BH];
              float v2 = (float)vbuf[vb + (size_t)(j + 2) * BH];
              float v3 = (float)vbuf[vb + (size_t)(j + 3) * BH];
              acc += sc[sq][h][0][j] * v0 + sc[sq][h][0][j + 1] * v1 +
                     sc[sq][h][0][j + 2] * v2 + sc[sq][h][0][j + 3] * v3;
            }
            for (; j < pos; j++)
              acc += sc[sq][h][0][j] * (float)vbuf[vb + (size_t)j * BH];
            acc += sc[sq][h][0][pos] * (float)v_cur[sq][0][col];
          } else {
            #pragma unroll
            for (int j = 0; j < 4; j++)
              acc += sc[sq][h][tok][j] * (float)v_cur[sq][j][col];
          }
          oh[sq][tok][col] = (_Float16)acc;
        }
      }
      __syncthreads();
      // ==== x += o @ Wo (split-K; split-s epilogue fuses xh + x^2) ====
      {
        const size_t wb = ((size_t)l * 48 + kg * 24) * BH + col;
        float ao[2][NT] = {};
        for (int j8 = 0; j8 < 24; j8 += 8) {
          W16 w[8];
          #pragma unroll
          for (int u = 0; u < 8; u++) w[u].v8 = Wo8[wb + (size_t)(j8 + u) * BH];
          #pragma unroll
          for (int u = 0; u < 8; u++)
            #pragma unroll
            for (int s = 0; s < 2; s++)
              #pragma unroll
              for (int tok = 0; tok < NT; tok++) {
                W16 hv; hv.v8 = *(const h8*)&oh[s][tok][(kg * 24 + j8 + u) * 8];
                #pragma unroll
                for (int r = 0; r < 4; r++)
                  ao[s][tok] = fdot2(hv.h[r], w[u].h[r], ao[s][tok]);
              }
        }
        {
          const int so = kg ^ 1;
          #pragma unroll
          for (int tok = 0; tok < NT; tok++) scr.wop[so][tok][col] = ao[so][tok];
        }
        __syncthreads();
        {
          const int s = kg;
          #pragma unroll
          for (int tok = 0; tok < NT; tok++) {
            float xn = xs[s][tok][col] + ao[s][tok] + scr.wop[s][tok][col];
            xs[s][tok][col] = xn; xh[s][tok][col] = (_Float16)xn;
            float r = xn * xn;
            #pragma unroll
            for (int off = 32; off; off >>= 1) r += __shfl_down(r, off, 64);
            if ((tid & 63) == 0) redsq[s][tok][w6] = r;
          }
        }
        __syncthreads();
      }
      // ==== x += gelu(sca2 * (x @ gW1)) @ W2 (gamma folded; sca2 at gelu) ====
      {
        float a1[2][NT][2] = {};
        for (int j8 = 0; j8 < 48; j8 += 4) {
          W16 w0[4], w1[4];
          #pragma unroll
          for (int u = 0; u < 4; u++) {
            w0[u].v8 = W18[((size_t)(l * 48 + j8 + u)) * (4 * BH) + tid];
            w1[u].v8 = W18[((size_t)(l * 48 + j8 + u)) * (4 * BH) + tid + NTH];
          }
          #pragma unroll
          for (int u = 0; u < 4; u++)
            #pragma unroll
            for (int s = 0; s < 2; s++)
              #pragma unroll
              for (int t = 0; t < NT; t++) {
                W16 hv; hv.v8 = *(const h8*)&xh[s][t][(j8 + u) * 8];
                #pragma unroll
                for (int r = 0; r < 4; r++) {
                  a1[s][t][0] = fdot2(hv.h[r], w0[u].h[r], a1[s][t][0]);
                  a1[s][t][1] = fdot2(hv.h[r], w1[u].h[r], a1[s][t][1]);
                }
              }
        }
        #pragma unroll
        for (int s = 0; s < 2; s++)
          #pragma unroll
          for (int t = 0; t < NT; t++) {
            float ss = redsq[s][t][0] + redsq[s][t][1] + redsq[s][t][2] +
                       redsq[s][t][3] + redsq[s][t][4] + redsq[s][t][5];
            float sca = rsqrtf(ss * (1.0f / BH) + 1e-5f);
            float z0 = a1[s][t][0] * sca, z1 = a1[s][t][1] * sca;
            scr.ffn.f1h[s][t][tid]       = (_Float16)(0.5f * z0 * (1.0f + erff(z0 * 0.7071067811865476f)));
            scr.ffn.f1h[s][t][tid + NTH] = (_Float16)(0.5f * z1 * (1.0f + erff(z1 * 0.7071067811865476f)));
          }
        __syncthreads();
        // W2: split-K; split-s epilogue fuses xh stage + x^2 sums
        {
          float a2[2][NT] = {};
          for (int j8 = 0; j8 < 96; j8 += 8) {
            W16 w[8];
            #pragma unroll
            for (int u = 0; u < 8; u++)
              w[u].v8 = W28[((size_t)(l * 192 + kg * 96 + j8 + u)) * BH + col];
            #pragma unroll
            for (int u = 0; u < 8; u++)
              #pragma unroll
              for (int s = 0; s < 2; s++)
                #pragma unroll
                for (int t = 0; t < NT; t++) {
                  W16 fv; fv.v8 = *(const h8*)&scr.ffn.f1h[s][t][(kg * 96 + j8 + u) * 8];
                  #pragma unroll
                  for (int r = 0; r < 4; r++)
                    a2[s][t] = fdot2(fv.h[r], w[u].h[r], a2[s][t]);
                }
          }
          {
            const int so = kg ^ 1;
            #pragma unroll
            for (int t = 0; t < NT; t++) scr.ffn.w2p[so][t][col] = a2[so][t];
          }
          __syncthreads();
          {
            const int s = kg;
            #pragma unroll
            for (int t = 0; t < NT; t++) {
              float xn = xs[s][t][col] + a2[s][t] + scr.ffn.w2p[s][t][col];
              xs[s][t][col] = xn; xh[s][t][col] = (_Float16)xn;
              float r = xn * xn;
              #pragma unroll
              for (int off = 32; off; off >>= 1) r += __shfl_down(r, off, 64);
              if ((tid & 63) == 0) redsq[s][t][w6] = r;
            }
          }
          __syncthreads();
        }
      }
    }
  };

  for (int i = 0; i < S_CNT; i++) {
    int grow;
    if (i == 0) { layers(IC<4>{}, 0, true);           grow = 3; }
    else        { layers(IC<1>{}, PP + i - 1, false); grow = 0; }

    // ---- phase A: argmax partials + next-token copy (fused f16 stage + sums) ----
    {
      float gen = xs[sq][grow][col];
      float v = gen; int idx = col;
      #pragma unroll
      for (int off = 32; off; off >>= 1) {
        float v2 = __shfl_down(v, off, 64); int i2 = __shfl_down(idx, off, 64);
        if (v2 > v || (v2 == v && i2 < idx)) { v = v2; idx = i2; }
      }
      if ((tid & 63) == 0) { redv[wid] = v; redi[wid] = idx; }
      float nxt = fin[sq] ? 0.0f : gen;
      xs[sq][0][col] = nxt; xh[sq][0][col] = (_Float16)nxt;
      float r = nxt * nxt;
      #pragma unroll
      for (int off = 32; off; off >>= 1) r += __shfl_down(r, off, 64);
      if ((tid & 63) == 0) redsq[sq][0][w6] = r;
      __syncthreads();
    }
    // ---- phase B: argmax finalize (+fin update by same thread) + fin-free logits ----
    {
      if (col == 0) {
        const int b = sq * 6;
        float bv = redv[b]; int bi = redi[b];
        for (int w = 1; w < 6; w++)
          if (redv[b + w] > bv || (redv[b + w] == bv && redi[b + w] < bi)) {
            bv = redv[b + w]; bi = redi[b + w];
          }
        if (bi == EOS_I) fin[sq] = 1;
      }
      if (col < NV) {
        float acc = 0.f;
        for (int j8 = 0; j8 < 48; j8 += 8) {
          W16 w[8];
          #pragma unroll
          for (int u = 0; u < 8; u++) w[u].v8 = Wlm8[(size_t)(j8 + u) * NV + col];
          #pragma unroll
          for (int u = 0; u < 8; u++) {
            W16 gv; gv.v8 = *(const h8*)&xh[sq][0][(j8 + u) * 8];
            #pragma unroll
            for (int r = 0; r < 4; r++) acc = fdot2(gv.h[r], w[u].h[r], acc);
          }
        }
        out[((size_t)(seq0 + sq) * S_CNT + i) * NV + col] = acc;
      }
      __syncthreads();
    }
  }
}

extern "C" void kernel_launch(void* const* d_in, const int* in_sizes, int n_in,
                              void* d_out, int out_size, void* d_ws, size_t ws_size,
                              hipStream_t stream) {
  const float* x     = (const float*)d_in[0];
  // d_in[1] = target (unused)
  const float* Wproj = (const float*)d_in[2];
  const float* an    = (const float*)d_in[3];
  const float* Wq    = (const float*)d_in[4];
  const float* Wk    = (const float*)d_in[5];
  const float* Wv    = (const float*)d_in[6];
  const float* Wo    = (const float*)d_in[7];
  const float* fn    = (const float*)d_in[8];
  const float* W1    = (const float*)d_in[9];
  const float* W2    = (const float*)d_in[10];
  const float* Wlm   = (const float*)d_in[11];
  float* out = (float*)d_out;
  (void)ws_size; (void)in_sizes; (void)n_in; (void)out_size;

  // ---- carve d_ws: h8-packed weights (gamma folded into Wq/Wk/Wv/W1), then f16 KV ----
  h8* w = (h8*)d_ws;
  const int n_proj = (H_IN / 8) * (PP * BH);
  const int n_qkvo = NL * (BH / 8) * BH;
  const int n_w1   = NL * (BH / 8) * (4 * BH);
  const int n_w2   = NL * (4 * BH / 8) * BH;
  const int n_lm   = (BH / 8) * NV;
  h8* Wproj_p = w;  w += n_proj;
  h8* Wq_p    = w;  w += n_qkvo;
  h8* Wk_p    = w;  w += n_qkvo;
  h8* Wv_p    = w;  w += n_qkvo;
  h8* Wo_p    = w;  w += n_qkvo;
  h8* W1_p    = w;  w += n_w1;
  h8* W2_p    = w;  w += n_w2;
  h8* Wlm_p   = w;  w += n_lm;
  const size_t kv_elems = (size_t)NSEQ * NL * TT * BH;
  _Float16* kbuf = (_Float16*)w;
  _Float16* vbuf = kbuf + kv_elems;

  auto pack = [&](const float* src, const float* g, h8* dst, int R, int C) {
    dim3 grid((C + 255) / 256, R / 8);
    pack8_kernel<<<grid, 256, 0, stream>>>(src, g, dst, C);
  };
  pack(Wproj, nullptr, Wproj_p, H_IN,        PP * BH);
  pack(Wq,    an,      Wq_p,    NL * BH,     BH);
  pack(Wk,    an,      Wk_p,    NL * BH,     BH);
  pack(Wv,    an,      Wv_p,    NL * BH,     BH);
  pack(Wo,    nullptr, Wo_p,    NL * BH,     BH);
  pack(W1,    fn,      W1_p,    NL * BH,     4 * BH);
  pack(W2,    nullptr, W2_p,    NL * 4 * BH, BH);
  pack(Wlm,   nullptr, Wlm_p,   BH,          NV);

  decoder_kernel<<<NSEQ / 2, NTH, 0, stream>>>(
      x, Wproj_p, Wq_p, Wk_p, Wv_p, Wo_p, W1_p, W2_p, Wlm_p, out, kbuf, vbuf);
}